// Round 5
// baseline (219.096 us; speedup 1.0000x reference)
//
#include <hip/hip_runtime.h>

typedef __attribute__((ext_vector_type(8))) short short8;
typedef _Float16 half8 __attribute__((ext_vector_type(8)));
typedef __attribute__((ext_vector_type(4))) float f32x4;
typedef __attribute__((ext_vector_type(4))) unsigned int uint4v;
typedef __attribute__((ext_vector_type(2))) unsigned int uint2v;

#define B_   8
#define LX_  2048
#define LY_  2048
#define D_   256
#define NROW (B_ * LX_)   // 16384
#define NQ   4            // LY quarters

__device__ __forceinline__ unsigned short f2bf(float f) {
  unsigned u = __builtin_bit_cast(unsigned, f);
  u += 0x7FFF + ((u >> 16) & 1);          // RNE truncate (inputs are finite)
  return (unsigned short)(u >> 16);
}
__device__ __forceinline__ float bf2f(unsigned short h) {
  unsigned u = ((unsigned)h) << 16;
  return __builtin_bit_cast(float, u);
}

// ---------------- W -> hi/lo bf16 split (65536 elems) ----------------
__global__ __launch_bounds__(256) void wsplit_kernel(
    const float* __restrict__ W, unsigned short* __restrict__ Whi,
    unsigned short* __restrict__ Wlo) {
  int i = blockIdx.x * 256 + threadIdx.x;
  float w = W[i];
  unsigned short hi = f2bf(w);
  Whi[i] = hi;
  Wlo[i] = f2bf(w - bf2f(hi));
}

// ---------------- proj = relu(in @ W^T + b), exact via bf16 hi/lo split
__global__ __launch_bounds__(256, 2) void proj_kernel(
    const float* __restrict__ X, const float* __restrict__ Y,
    const float* __restrict__ bias,
    const unsigned short* __restrict__ Whi, const unsigned short* __restrict__ Wlo,
    _Float16* __restrict__ XP, _Float16* __restrict__ YP) {
  __shared__ unsigned short Ah[64][40], Al[64][40];
  __shared__ unsigned short Bh[256][40], Bl[256][40];

  int t = threadIdx.x;
  int lane = t & 63, wave = t >> 6;
  int q = lane >> 4, n15 = lane & 15;

  const float* src;
  _Float16* dst;
  int m0;
  if (blockIdx.x < 256) { src = X; dst = XP; m0 = blockIdx.x * 64; }
  else                  { src = Y; dst = YP; m0 = (blockIdx.x - 256) * 64; }

  f32x4 acc[4][4];
  for (int mt = 0; mt < 4; ++mt)
    for (int nt = 0; nt < 4; ++nt) acc[mt][nt] = (f32x4){0.f, 0.f, 0.f, 0.f};

  int arow = t >> 2;
  int aseg = t & 3;
  int erow = t >> 2, ec = t & 3;

  for (int kc = 0; kc < 8; ++kc) {
    __syncthreads();
    for (int i = 0; i < 2; ++i) {
      int seg = aseg + i * 4;
      f32x4 f = *(const f32x4*)(src + (size_t)(m0 + arow) * D_ + kc * 32 + seg * 4);
      unsigned short h[4], l[4];
      for (int j = 0; j < 4; ++j) {
        h[j] = f2bf(f[j]);
        l[j] = f2bf(f[j] - bf2f(h[j]));
      }
      uint2v vh = {(unsigned)h[0] | ((unsigned)h[1] << 16),
                   (unsigned)h[2] | ((unsigned)h[3] << 16)};
      uint2v vl = {(unsigned)l[0] | ((unsigned)l[1] << 16),
                   (unsigned)l[2] | ((unsigned)l[3] << 16)};
      *(uint2v*)&Ah[arow][seg * 4] = vh;
      *(uint2v*)&Al[arow][seg * 4] = vl;
    }
    for (int pass = 0; pass < 4; ++pass) {
      int e = pass * 64 + erow;
      uint4v vh = *(const uint4v*)(Whi + (size_t)e * D_ + kc * 32 + ec * 8);
      uint4v vl = *(const uint4v*)(Wlo + (size_t)e * D_ + kc * 32 + ec * 8);
      *(uint4v*)&Bh[e][ec * 8] = vh;
      *(uint4v*)&Bl[e][ec * 8] = vl;
    }
    __syncthreads();
    short8 afh[4], afl[4], bfh[4], bfl[4];
    for (int mt = 0; mt < 4; ++mt) {
      afh[mt] = *(const short8*)&Ah[mt * 16 + n15][q * 8];
      afl[mt] = *(const short8*)&Al[mt * 16 + n15][q * 8];
    }
    for (int nt = 0; nt < 4; ++nt) {
      bfh[nt] = *(const short8*)&Bh[wave * 64 + nt * 16 + n15][q * 8];
      bfl[nt] = *(const short8*)&Bl[wave * 64 + nt * 16 + n15][q * 8];
    }
    for (int mt = 0; mt < 4; ++mt)
      for (int nt = 0; nt < 4; ++nt) {
        acc[mt][nt] = __builtin_amdgcn_mfma_f32_16x16x32_bf16(afh[mt], bfh[nt], acc[mt][nt], 0, 0, 0);
        acc[mt][nt] = __builtin_amdgcn_mfma_f32_16x16x32_bf16(afl[mt], bfh[nt], acc[mt][nt], 0, 0, 0);
        acc[mt][nt] = __builtin_amdgcn_mfma_f32_16x16x32_bf16(afh[mt], bfl[nt], acc[mt][nt], 0, 0, 0);
      }
  }

  for (int nt = 0; nt < 4; ++nt) {
    int e = wave * 64 + nt * 16 + n15;
    float bv = bias[e];
    for (int mt = 0; mt < 4; ++mt)
      for (int r = 0; r < 4; ++r) {
        float v = acc[mt][nt][r] + bv;
        v = v > 0.f ? v : 0.f;
        dst[(size_t)(m0 + mt * 16 + q * 4 + r) * D_ + e] = (_Float16)v;
      }
  }
}

// ---------------- y fp32 [B][LY][D] -> yT fp16 [B][D][LY] -------------
__global__ __launch_bounds__(256) void transpose_kernel(
    const float* __restrict__ Y, _Float16* __restrict__ YT) {
  __shared__ _Float16 tile[64][72];
  int id = blockIdx.x;
  int db = id & 3, nb = (id >> 2) & 31, b = id >> 7;
  int t = threadIdx.x;
  int nl = t >> 2, ds = t & 3;
  const float* src = Y + (size_t)(b * LY_ + nb * 64 + nl) * D_ + db * 64 + ds * 16;
  for (int i = 0; i < 4; ++i) {
    f32x4 f = *(const f32x4*)(src + i * 4);
    for (int j = 0; j < 4; ++j) tile[ds * 16 + i * 4 + j][nl] = (_Float16)f[j];
  }
  __syncthreads();
  int dl = t >> 2, nsub = t & 3;
  uint4v v0 = *(const uint4v*)&tile[dl][nsub * 16];
  uint4v v1 = *(const uint4v*)&tile[dl][nsub * 16 + 8];
  _Float16* dst = YT + (size_t)(b * D_ + db * 64 + dl) * LY_ + nb * 64 + nsub * 16;
  *(uint4v*)(dst) = v0;
  *(uint4v*)(dst + 8) = v1;
}

// ---------------- flash attention, split-LY quarters ------------------
// grid 512: (b, 128 x-rows, LY-quarter). 4 waves x 32 rows. y tiles of 32.
// Each B-frag ds_read feeds 2 MFMAs (2 m-tiles); l via ones-column MFMA.
__global__ __launch_bounds__(256, 2) void flash_kernel(
    const _Float16* __restrict__ XP, const _Float16* __restrict__ YP,
    const _Float16* __restrict__ YT, const int* __restrict__ MASK,
    _Float16* __restrict__ PO, float* __restrict__ Pm, float* __restrict__ Pl) {
  __shared__ _Float16 yp_t[32][264];   // [n][d], +8 pad
  __shared__ _Float16 yT_t[256][40];   // [d][n], +8 pad
  __shared__ _Float16 pbuf[4][32][40]; // per-wave P round-trip (2 m-tiles)
  __shared__ int msk[32];

  int t = threadIdx.x;
  int lane = t & 63, wave = t >> 6;
  int q = lane >> 4, n15 = lane & 15;
  int qtr = blockIdx.x & 3;
  int xg = (blockIdx.x >> 2) & 15;
  int b = blockIdx.x >> 6;
  int row0 = xg * 128 + wave * 32;
  int y_start = qtr * (LY_ / NQ);

  // x_proj A-fragments for this wave's 32 rows (2 m-tiles), resident
  half8 a0[8], a1[8];
  {
    const _Float16* x0 = XP + (size_t)(b * LX_ + row0 + n15) * D_ + q * 8;
    const _Float16* x1 = XP + (size_t)(b * LX_ + row0 + 16 + n15) * D_ + q * 8;
    for (int kk = 0; kk < 8; ++kk) {
      a0[kk] = *(const half8*)(x0 + kk * 32);
      a1[kk] = *(const half8*)(x1 + kk * 32);
    }
  }

  // ones B-frag: output col 0 sums p over k (l accumulator)
  half8 lones;
  for (int j = 0; j < 8; ++j) lones[j] = (n15 == 0) ? (_Float16)1 : (_Float16)0;

  float m_r[2][4];
  f32x4 lacc[2];
  for (int mt = 0; mt < 2; ++mt) {
    for (int r = 0; r < 4; ++r) m_r[mt][r] = -1e30f;
    lacc[mt] = (f32x4){0.f, 0.f, 0.f, 0.f};
  }
  f32x4 oacc[2][16];
  for (int mt = 0; mt < 2; ++mt)
    for (int dt = 0; dt < 16; ++dt) oacc[mt][dt] = (f32x4){0.f, 0.f, 0.f, 0.f};

  const _Float16* ypb = YP + (size_t)b * LY_ * D_;
  const _Float16* yTb = YT + (size_t)b * D_ * LY_;
  const int* mb = MASK + b * LY_;

  for (int y0 = y_start; y0 < y_start + LY_ / NQ; y0 += 32) {
    __syncthreads();
    // stage y_proj tile [32][256] fp16
    for (int i = 0; i < 4; ++i) {
      int c = t + i * 256;
      int n = c >> 5, dc = c & 31;
      uint4v v = *(const uint4v*)(ypb + (size_t)(y0 + n) * D_ + dc * 8);
      *(uint4v*)&yp_t[n][dc * 8] = v;
    }
    // stage yT tile [256][32] fp16
    for (int i = 0; i < 4; ++i) {
      int c = t + i * 256;
      int d = c >> 2, nc = c & 3;
      uint4v v = *(const uint4v*)(yTb + (size_t)d * LY_ + y0 + nc * 8);
      *(uint4v*)&yT_t[d][nc * 8] = v;
    }
    if (t < 32) msk[t] = mb[y0 + t];
    __syncthreads();

    // ---- QK^T : S[32m x 32n]; each B-frag read feeds both m-tiles
    f32x4 S00 = {0.f,0.f,0.f,0.f}, S01 = {0.f,0.f,0.f,0.f};
    f32x4 S10 = {0.f,0.f,0.f,0.f}, S11 = {0.f,0.f,0.f,0.f};
    for (int kk = 0; kk < 8; ++kk) {
      half8 b0 = *(const half8*)&yp_t[n15][kk * 32 + q * 8];
      half8 b1 = *(const half8*)&yp_t[16 + n15][kk * 32 + q * 8];
      S00 = __builtin_amdgcn_mfma_f32_16x16x32_f16(a0[kk], b0, S00, 0, 0, 0);
      S01 = __builtin_amdgcn_mfma_f32_16x16x32_f16(a0[kk], b1, S01, 0, 0, 0);
      S10 = __builtin_amdgcn_mfma_f32_16x16x32_f16(a1[kk], b0, S10, 0, 0, 0);
      S11 = __builtin_amdgcn_mfma_f32_16x16x32_f16(a1[kk], b1, S11, 0, 0, 0);
    }
    int mk0 = msk[n15], mk1 = msk[16 + n15];

    // ---- online softmax per m-tile: max-shfl only, l comes from MFMA
    for (int mt = 0; mt < 2; ++mt) {
      const f32x4& Sa = mt ? S10 : S00;
      const f32x4& Sb = mt ? S11 : S01;
      float al[4];
      _Float16 ph0[4], ph1[4];
      bool need = false;
      for (int r = 0; r < 4; ++r) {
        float s0 = mk0 ? -1e30f : Sa[r];
        float s1 = mk1 ? -1e30f : Sb[r];
        float tm = fmaxf(s0, s1);
        tm = fmaxf(tm, __shfl_xor(tm, 1));
        tm = fmaxf(tm, __shfl_xor(tm, 2));
        tm = fmaxf(tm, __shfl_xor(tm, 4));
        tm = fmaxf(tm, __shfl_xor(tm, 8));
        float mn = fmaxf(m_r[mt][r], tm);
        al[r] = __expf(m_r[mt][r] - mn);
        m_r[mt][r] = mn;
        ph0[r] = (_Float16)__expf(s0 - mn);
        ph1[r] = (_Float16)__expf(s1 - mn);
        need = need || (al[r] != 1.0f);
      }
      if (__ballot(need)) {
        for (int dt = 0; dt < 16; ++dt)
          for (int r = 0; r < 4; ++r) oacc[mt][dt][r] *= al[r];
        for (int r = 0; r < 4; ++r) lacc[mt][r] *= al[r];
      }
      for (int r = 0; r < 4; ++r) {
        pbuf[wave][mt * 16 + q * 4 + r][n15] = ph0[r];
        pbuf[wave][mt * 16 + q * 4 + r][16 + n15] = ph1[r];
      }
    }
    // ---- P round-trip: C-layout -> LDS -> A-layout
    half8 pa0 = *(const half8*)&pbuf[wave][n15][q * 8];
    half8 pa1 = *(const half8*)&pbuf[wave][16 + n15][q * 8];
    // ---- l += P @ ones (exact fp16-p sum, alpha-consistent)
    lacc[0] = __builtin_amdgcn_mfma_f32_16x16x32_f16(pa0, lones, lacc[0], 0, 0, 0);
    lacc[1] = __builtin_amdgcn_mfma_f32_16x16x32_f16(pa1, lones, lacc[1], 0, 0, 0);
    // ---- PV: each B-frag read feeds both m-tiles
    for (int dt = 0; dt < 16; ++dt) {
      half8 bb = *(const half8*)&yT_t[dt * 16 + n15][q * 8];
      oacc[0][dt] = __builtin_amdgcn_mfma_f32_16x16x32_f16(pa0, bb, oacc[0][dt], 0, 0, 0);
      oacc[1][dt] = __builtin_amdgcn_mfma_f32_16x16x32_f16(pa1, bb, oacc[1][dt], 0, 0, 0);
    }
  }

  // epilogue: unnormalized numerator (fp16) + per-row m,l (fp32)
  size_t prow = (size_t)(qtr * B_ + b) * LX_ + row0;
  _Float16* po = PO + prow * D_;
  for (int mt = 0; mt < 2; ++mt)
    for (int dt = 0; dt < 16; ++dt)
      for (int r = 0; r < 4; ++r)
        po[(size_t)(mt * 16 + q * 4 + r) * D_ + dt * 16 + n15] = (_Float16)oacc[mt][dt][r];
  if (n15 == 0) {
    for (int mt = 0; mt < 2; ++mt)
      for (int r = 0; r < 4; ++r) {
        Pm[prow + mt * 16 + q * 4 + r] = m_r[mt][r];
        Pl[prow + mt * 16 + q * 4 + r] = lacc[mt][r];
      }
  }
}

// ---------------- merge the four LY-quarter partials ------------------
__global__ __launch_bounds__(256) void merge_kernel(
    const _Float16* __restrict__ PO, const float* __restrict__ Pm,
    const float* __restrict__ Pl, float* __restrict__ OUT) {
  int c = blockIdx.x * 256 + threadIdx.x;  // [0, 524288)
  int row = c >> 5, seg = c & 31;
  float m = -1e30f;
  float mh[NQ], lh[NQ];
  for (int h = 0; h < NQ; ++h) {
    mh[h] = Pm[(size_t)h * NROW + row];
    lh[h] = Pl[(size_t)h * NROW + row];
    m = fmaxf(m, mh[h]);
  }
  float l = 0.f;
  float wh[NQ];
  for (int h = 0; h < NQ; ++h) {
    wh[h] = __expf(mh[h] - m);
    l += lh[h] * wh[h];
  }
  float inv = 1.0f / l;
  float o[8];
  for (int j = 0; j < 8; ++j) o[j] = 0.f;
  for (int h = 0; h < NQ; ++h) {
    half8 a = *(const half8*)(PO + ((size_t)h * NROW + row) * D_ + seg * 8);
    float w = wh[h];
    for (int j = 0; j < 8; ++j) o[j] += (float)a[j] * w;
  }
  float* op = OUT + (size_t)row * D_ + seg * 8;
  f32x4 o0 = {o[0] * inv, o[1] * inv, o[2] * inv, o[3] * inv};
  f32x4 o1 = {o[4] * inv, o[5] * inv, o[6] * inv, o[7] * inv};
  *(f32x4*)op = o0;
  *(f32x4*)(op + 4) = o1;
}

extern "C" void kernel_launch(void* const* d_in, const int* in_sizes, int n_in,
                              void* d_out, int out_size, void* d_ws, size_t ws_size,
                              hipStream_t stream) {
  const float* x     = (const float*)d_in[0];  // [8,2048,256]
  const float* y     = (const float*)d_in[1];  // [8,2048,256]
  const int*   ymask = (const int*)  d_in[2];  // [8,2048]
  const float* W     = (const float*)d_in[3];  // [256,256]
  const float* bias  = (const float*)d_in[4];  // [256]
  float* out = (float*)d_out;

  // ws layout (~57 MB total)
  char* ws = (char*)d_ws;
  unsigned short* Whi = (unsigned short*)(ws);                    // 128 KB
  unsigned short* Wlo = (unsigned short*)(ws + 131072);           // 128 KB
  _Float16* XP  = (_Float16*)(ws + 262144);                       // 8 MB
  _Float16* YP  = (_Float16*)(ws + 262144 + 8388608);             // 8 MB
  _Float16* YT  = (_Float16*)(ws + 262144 + 2 * 8388608);         // 8 MB
  _Float16* PO  = (_Float16*)(ws + 262144 + 3 * 8388608);         // 32 MB (4 quarters)
  float*    Pm  = (float*)   (ws + 262144 + 3 * 8388608 + 33554432);   // 256 KB
  float*    Pl  = (float*)   (ws + 262144 + 3 * 8388608 + 33554432 + 262144);

  wsplit_kernel<<<256, 256, 0, stream>>>(W, Whi, Wlo);
  proj_kernel<<<512, 256, 0, stream>>>(x, y, bias, Whi, Wlo, XP, YP);
  transpose_kernel<<<1024, 256, 0, stream>>>(y, YT);
  flash_kernel<<<512, 256, 0, stream>>>(XP, YP, YT, ymask, PO, Pm, Pl);
  merge_kernel<<<2048, 256, 0, stream>>>(PO, Pm, Pl, out);
}

// Round 6
// 161.920 us; speedup vs baseline: 1.3531x; 1.3531x over previous
//
#include <hip/hip_runtime.h>

typedef __attribute__((ext_vector_type(8))) short short8;
typedef _Float16 half8 __attribute__((ext_vector_type(8)));
typedef __attribute__((ext_vector_type(4))) float f32x4;
typedef __attribute__((ext_vector_type(4))) unsigned int uint4v;
typedef __attribute__((ext_vector_type(2))) unsigned int uint2v;

#define B_   8
#define LX_  2048
#define LY_  2048
#define D_   256
#define NROW (B_ * LX_)   // 16384

__device__ __forceinline__ unsigned short f2bf(float f) {
  unsigned u = __builtin_bit_cast(unsigned, f);
  u += 0x7FFF + ((u >> 16) & 1);          // RNE truncate (inputs are finite)
  return (unsigned short)(u >> 16);
}
__device__ __forceinline__ float bf2f(unsigned short h) {
  unsigned u = ((unsigned)h) << 16;
  return __builtin_bit_cast(float, u);
}

// ---------------- W -> hi/lo bf16 split (65536 elems) ----------------
__global__ __launch_bounds__(256) void wsplit_kernel(
    const float* __restrict__ W, unsigned short* __restrict__ Whi,
    unsigned short* __restrict__ Wlo) {
  int i = blockIdx.x * 256 + threadIdx.x;
  float w = W[i];
  unsigned short hi = f2bf(w);
  Whi[i] = hi;
  Wlo[i] = f2bf(w - bf2f(hi));
}

// ---------------- per-batch mask compaction: prefix scan --------------
// keep j where mask==0 (reference drops mask==1). 1 block per batch.
__global__ __launch_bounds__(256) void scan_kernel(
    const int* __restrict__ MASK, int* __restrict__ CIDX, int* __restrict__ Lc) {
  __shared__ int s[256];
  __shared__ int base_s[256];
  int b = blockIdx.x, t = threadIdx.x;
  int f[8];
  int cnt = 0;
  for (int k = 0; k < 8; ++k) {
    f[k] = (MASK[b * 2048 + t * 8 + k] == 0) ? 1 : 0;
    cnt += f[k];
  }
  s[t] = cnt;
  __syncthreads();
  if (t == 0) {
    int run = 0;
    for (int i = 0; i < 256; ++i) { int v = s[i]; base_s[i] = run; run += v; }
    Lc[b] = run;
  }
  __syncthreads();
  int off = base_s[t];
  for (int k = 0; k < 8; ++k)
    if (f[k]) CIDX[b * 2048 + (off++)] = t * 8 + k;
}

// ---------------- proj = relu(in @ W^T + b), exact via bf16 hi/lo split
__global__ __launch_bounds__(256, 2) void proj_kernel(
    const float* __restrict__ X, const float* __restrict__ Y,
    const float* __restrict__ bias,
    const unsigned short* __restrict__ Whi, const unsigned short* __restrict__ Wlo,
    _Float16* __restrict__ XP, _Float16* __restrict__ YP) {
  __shared__ unsigned short Ah[64][40], Al[64][40];
  __shared__ unsigned short Bh[256][40], Bl[256][40];

  int t = threadIdx.x;
  int lane = t & 63, wave = t >> 6;
  int q = lane >> 4, n15 = lane & 15;

  const float* src;
  _Float16* dst;
  int m0;
  if (blockIdx.x < 256) { src = X; dst = XP; m0 = blockIdx.x * 64; }
  else                  { src = Y; dst = YP; m0 = (blockIdx.x - 256) * 64; }

  f32x4 acc[4][4];
  for (int mt = 0; mt < 4; ++mt)
    for (int nt = 0; nt < 4; ++nt) acc[mt][nt] = (f32x4){0.f, 0.f, 0.f, 0.f};

  int arow = t >> 2;
  int aseg = t & 3;
  int erow = t >> 2, ec = t & 3;

  for (int kc = 0; kc < 8; ++kc) {
    __syncthreads();
    for (int i = 0; i < 2; ++i) {
      int seg = aseg + i * 4;
      f32x4 f = *(const f32x4*)(src + (size_t)(m0 + arow) * D_ + kc * 32 + seg * 4);
      unsigned short h[4], l[4];
      for (int j = 0; j < 4; ++j) {
        h[j] = f2bf(f[j]);
        l[j] = f2bf(f[j] - bf2f(h[j]));
      }
      uint2v vh = {(unsigned)h[0] | ((unsigned)h[1] << 16),
                   (unsigned)h[2] | ((unsigned)h[3] << 16)};
      uint2v vl = {(unsigned)l[0] | ((unsigned)l[1] << 16),
                   (unsigned)l[2] | ((unsigned)l[3] << 16)};
      *(uint2v*)&Ah[arow][seg * 4] = vh;
      *(uint2v*)&Al[arow][seg * 4] = vl;
    }
    for (int pass = 0; pass < 4; ++pass) {
      int e = pass * 64 + erow;
      uint4v vh = *(const uint4v*)(Whi + (size_t)e * D_ + kc * 32 + ec * 8);
      uint4v vl = *(const uint4v*)(Wlo + (size_t)e * D_ + kc * 32 + ec * 8);
      *(uint4v*)&Bh[e][ec * 8] = vh;
      *(uint4v*)&Bl[e][ec * 8] = vl;
    }
    __syncthreads();
    short8 afh[4], afl[4], bfh[4], bfl[4];
    for (int mt = 0; mt < 4; ++mt) {
      afh[mt] = *(const short8*)&Ah[mt * 16 + n15][q * 8];
      afl[mt] = *(const short8*)&Al[mt * 16 + n15][q * 8];
    }
    for (int nt = 0; nt < 4; ++nt) {
      bfh[nt] = *(const short8*)&Bh[wave * 64 + nt * 16 + n15][q * 8];
      bfl[nt] = *(const short8*)&Bl[wave * 64 + nt * 16 + n15][q * 8];
    }
    for (int mt = 0; mt < 4; ++mt)
      for (int nt = 0; nt < 4; ++nt) {
        acc[mt][nt] = __builtin_amdgcn_mfma_f32_16x16x32_bf16(afh[mt], bfh[nt], acc[mt][nt], 0, 0, 0);
        acc[mt][nt] = __builtin_amdgcn_mfma_f32_16x16x32_bf16(afl[mt], bfh[nt], acc[mt][nt], 0, 0, 0);
        acc[mt][nt] = __builtin_amdgcn_mfma_f32_16x16x32_bf16(afh[mt], bfl[nt], acc[mt][nt], 0, 0, 0);
      }
  }

  for (int nt = 0; nt < 4; ++nt) {
    int e = wave * 64 + nt * 16 + n15;
    float bv = bias[e];
    for (int mt = 0; mt < 4; ++mt)
      for (int r = 0; r < 4; ++r) {
        float v = acc[mt][nt][r] + bv;
        v = v > 0.f ? v : 0.f;
        dst[(size_t)(m0 + mt * 16 + q * 4 + r) * D_ + e] = (_Float16)v;
      }
  }
}

// ---------------- gather compacted y_proj rows ------------------------
__global__ __launch_bounds__(256) void gather_rows_kernel(
    const _Float16* __restrict__ YP, const int* __restrict__ CIDX,
    const int* __restrict__ Lc, _Float16* __restrict__ YPc) {
  int g = blockIdx.x * 256 + threadIdx.x;   // [0, 524288)
  int rowid = g >> 5, seg = g & 31;
  int b = rowid >> 11, j = rowid & 2047;
  int idx = (j < Lc[b]) ? CIDX[b * 2048 + j] : 0;
  uint4v v = *(const uint4v*)(YP + ((size_t)(b << 11) + idx) * D_ + seg * 8);
  *(uint4v*)(YPc + (size_t)rowid * D_ + seg * 8) = v;
}

// ---------------- gather+transpose raw y -> YTc fp16 [B][D][j] --------
__global__ __launch_bounds__(256) void gatherT_kernel(
    const float* __restrict__ Y, const int* __restrict__ CIDX,
    const int* __restrict__ Lc, _Float16* __restrict__ YTc) {
  __shared__ _Float16 tile[64][72];
  int id = blockIdx.x;
  int db = id & 3, nb = (id >> 2) & 31, b = id >> 7;
  int t = threadIdx.x;
  int nl = t >> 2, ds = t & 3;
  int j = nb * 64 + nl;
  int idx = (j < Lc[b]) ? CIDX[b * 2048 + j] : 0;
  const float* src = Y + (size_t)(b * LY_ + idx) * D_ + db * 64 + ds * 16;
  for (int i = 0; i < 4; ++i) {
    f32x4 f = *(const f32x4*)(src + i * 4);
    for (int k = 0; k < 4; ++k) tile[ds * 16 + i * 4 + k][nl] = (_Float16)f[k];
  }
  __syncthreads();
  int dl = t >> 2, nsub = t & 3;
  uint4v v0 = *(const uint4v*)&tile[dl][nsub * 16];
  uint4v v1 = *(const uint4v*)&tile[dl][nsub * 16 + 8];
  _Float16* dst = YTc + (size_t)(b * D_ + db * 64 + dl) * LY_ + nb * 64 + nsub * 16;
  *(uint4v*)(dst) = v0;
  *(uint4v*)(dst + 8) = v1;
}

// ---------------- flash attention over COMPACTED y, split halves ------
// grid 512: (b, 64 x-rows, tile-half). 4 waves x 16 rows. tiles of 32 j.
// Register-prefetch pipeline; l via ones-column MFMA; tail mask by j>=Lc.
__global__ __launch_bounds__(256, 2) void flash_kernel(
    const _Float16* __restrict__ XP, const _Float16* __restrict__ YPc,
    const _Float16* __restrict__ YTc, const int* __restrict__ Lc,
    _Float16* __restrict__ PO, float* __restrict__ Pm, float* __restrict__ Pl) {
  __shared__ _Float16 yp_t[32][264];   // [j][d], +8 pad (row 528 B)
  __shared__ _Float16 yT_t[256][40];   // [d][j], +8 pad (row 80 B)
  __shared__ _Float16 pbuf[4][16][40]; // per-wave P round-trip

  int t = threadIdx.x;
  int lane = t & 63, wave = t >> 6;
  int q = lane >> 4, n15 = lane & 15;
  int half = blockIdx.x & 1;
  int xb = (blockIdx.x >> 1) & 31;
  int b = blockIdx.x >> 6;
  int row0 = xb * 64 + wave * 16;

  int lc = Lc[b];
  int T  = (lc + 31) >> 5;
  int T0 = (T + 1) >> 1;
  int tstart = half ? T0 : 0;
  int tend   = half ? T  : T0;

  half8 a[8];
  const _Float16* xrow = XP + (size_t)(b * LX_ + row0 + n15) * D_ + q * 8;
  for (int kk = 0; kk < 8; ++kk) a[kk] = *(const half8*)(xrow + kk * 32);

  half8 lones;
  for (int j = 0; j < 8; ++j) lones[j] = (n15 == 0) ? (_Float16)1 : (_Float16)0;

  float m_r[4];
  for (int r = 0; r < 4; ++r) m_r[r] = -1e30f;
  f32x4 lacc = {0.f, 0.f, 0.f, 0.f};
  f32x4 oacc[16];
  for (int dt = 0; dt < 16; ++dt) oacc[dt] = (f32x4){0.f, 0.f, 0.f, 0.f};

  const _Float16* ypb = YPc + (size_t)b * LY_ * D_;
  const _Float16* yTb = YTc + (size_t)b * D_ * LY_;

  uint4v pr[8];
#define PREFETCH(tt)                                                          \
  {                                                                           \
    int y0p = (tt) * 32;                                                      \
    for (int i = 0; i < 4; ++i) {                                             \
      int c = t + i * 256;                                                    \
      pr[i] = *(const uint4v*)(ypb + (size_t)(y0p + (c >> 5)) * D_ + (c & 31) * 8); \
    }                                                                         \
    for (int i = 0; i < 4; ++i) {                                             \
      int c = t + i * 256;                                                    \
      pr[4 + i] = *(const uint4v*)(yTb + (size_t)(c >> 2) * LY_ + y0p + (c & 3) * 8); \
    }                                                                         \
  }

  if (tstart < tend) PREFETCH(tstart);

  for (int tt = tstart; tt < tend; ++tt) {
    int y0 = tt * 32;
    __syncthreads();            // all waves done computing previous tile
    for (int i = 0; i < 4; ++i) {
      int c = t + i * 256;
      *(uint4v*)&yp_t[c >> 5][(c & 31) * 8] = pr[i];
    }
    for (int i = 0; i < 4; ++i) {
      int c = t + i * 256;
      *(uint4v*)&yT_t[c >> 2][(c & 3) * 8] = pr[4 + i];
    }
    if (tt + 1 < tend) PREFETCH(tt + 1);  // async, lands during compute
    __syncthreads();            // staging visible

    // ---- QK^T : S[16m x 32n]
    f32x4 S0 = {0.f, 0.f, 0.f, 0.f}, S1 = {0.f, 0.f, 0.f, 0.f};
    for (int kk = 0; kk < 8; ++kk) {
      half8 b0 = *(const half8*)&yp_t[n15][kk * 32 + q * 8];
      S0 = __builtin_amdgcn_mfma_f32_16x16x32_f16(a[kk], b0, S0, 0, 0, 0);
    }
    for (int kk = 0; kk < 8; ++kk) {
      half8 b1 = *(const half8*)&yp_t[16 + n15][kk * 32 + q * 8];
      S1 = __builtin_amdgcn_mfma_f32_16x16x32_f16(a[kk], b1, S1, 0, 0, 0);
    }
    bool mk0 = (y0 + n15) >= lc;        // computed tail predicate, no loads
    bool mk1 = (y0 + 16 + n15) >= lc;

    // ---- online softmax: max-shfl only; l comes from ones-MFMA
    float al[4];
    _Float16 ph0[4], ph1[4];
    bool need = false;
    for (int r = 0; r < 4; ++r) {
      float s0 = mk0 ? -1e30f : S0[r];
      float s1 = mk1 ? -1e30f : S1[r];
      float tm = fmaxf(s0, s1);
      tm = fmaxf(tm, __shfl_xor(tm, 1));
      tm = fmaxf(tm, __shfl_xor(tm, 2));
      tm = fmaxf(tm, __shfl_xor(tm, 4));
      tm = fmaxf(tm, __shfl_xor(tm, 8));
      float mn = fmaxf(m_r[r], tm);
      al[r] = __expf(m_r[r] - mn);
      m_r[r] = mn;
      ph0[r] = (_Float16)__expf(s0 - mn);
      ph1[r] = (_Float16)__expf(s1 - mn);
      need = need || (al[r] != 1.0f);
    }
    if (__ballot(need)) {
      for (int dt = 0; dt < 16; ++dt)
        for (int r = 0; r < 4; ++r) oacc[dt][r] *= al[r];
      for (int r = 0; r < 4; ++r) lacc[r] *= al[r];
    }
    // ---- P: C-layout -> LDS -> A-layout (wave-local, in-order DS pipe)
    for (int r = 0; r < 4; ++r) {
      pbuf[wave][q * 4 + r][n15] = ph0[r];
      pbuf[wave][q * 4 + r][16 + n15] = ph1[r];
    }
    half8 pa = *(const half8*)&pbuf[wave][n15][q * 8];
    // ---- l += P @ ones (exact fp16-p sum, alpha-consistent)
    lacc = __builtin_amdgcn_mfma_f32_16x16x32_f16(pa, lones, lacc, 0, 0, 0);
    // ---- PV
    for (int dt = 0; dt < 16; ++dt) {
      half8 bb = *(const half8*)&yT_t[dt * 16 + n15][q * 8];
      oacc[dt] = __builtin_amdgcn_mfma_f32_16x16x32_f16(pa, bb, oacc[dt], 0, 0, 0);
    }
  }
#undef PREFETCH

  // epilogue: unnormalized numerator (fp16) + per-row m,l (fp32)
  size_t prow = (size_t)(half * B_ + b) * LX_ + row0;
  _Float16* po = PO + prow * D_;
  for (int dt = 0; dt < 16; ++dt)
    for (int r = 0; r < 4; ++r)
      po[(size_t)(q * 4 + r) * D_ + dt * 16 + n15] = (_Float16)oacc[dt][r];
  if (n15 == 0) {
    for (int r = 0; r < 4; ++r) {
      Pm[prow + q * 4 + r] = m_r[r];
      Pl[prow + q * 4 + r] = lacc[r];
    }
  }
}

// ---------------- merge the two tile-half partials --------------------
__global__ __launch_bounds__(256) void merge_kernel(
    const _Float16* __restrict__ PO, const float* __restrict__ Pm,
    const float* __restrict__ Pl, float* __restrict__ OUT) {
  int c = blockIdx.x * 256 + threadIdx.x;  // [0, 524288)
  int row = c >> 5, seg = c & 31;
  float m0 = Pm[row], m1 = Pm[NROW + row];
  float l0 = Pl[row], l1 = Pl[NROW + row];
  float m = fmaxf(m0, m1);
  float w0 = __expf(m0 - m), w1 = __expf(m1 - m);
  float inv = 1.0f / (l0 * w0 + l1 * w1);
  const _Float16* p0 = PO + (size_t)row * D_ + seg * 8;
  const _Float16* p1 = p0 + (size_t)NROW * D_;
  half8 a = *(const half8*)p0;
  half8 bsec = *(const half8*)p1;
  float* o = OUT + (size_t)row * D_ + seg * 8;
  f32x4 o0, o1;
  for (int j = 0; j < 4; ++j) o0[j] = ((float)a[j] * w0 + (float)bsec[j] * w1) * inv;
  for (int j = 0; j < 4; ++j) o1[j] = ((float)a[4 + j] * w0 + (float)bsec[4 + j] * w1) * inv;
  *(f32x4*)o = o0;
  *(f32x4*)(o + 4) = o1;
}

extern "C" void kernel_launch(void* const* d_in, const int* in_sizes, int n_in,
                              void* d_out, int out_size, void* d_ws, size_t ws_size,
                              hipStream_t stream) {
  const float* x     = (const float*)d_in[0];  // [8,2048,256]
  const float* y     = (const float*)d_in[1];  // [8,2048,256]
  const int*   ymask = (const int*)  d_in[2];  // [8,2048]
  const float* W     = (const float*)d_in[3];  // [256,256]
  const float* bias  = (const float*)d_in[4];  // [256]
  float* out = (float*)d_out;

  // ws layout (~48.7 MB total)
  char* ws = (char*)d_ws;
  unsigned short* Whi = (unsigned short*)(ws);                     // 128 KB
  unsigned short* Wlo = (unsigned short*)(ws + 131072);            // 128 KB
  _Float16* XP  = (_Float16*)(ws + 262144);                        // 8 MB
  _Float16* YP  = (_Float16*)(ws + 262144 + 8388608);              // 8 MB
  _Float16* YPc = (_Float16*)(ws + 262144 + 2 * 8388608);          // 8 MB
  _Float16* YTc = (_Float16*)(ws + 262144 + 3 * 8388608);          // 8 MB
  _Float16* PO  = (_Float16*)(ws + 262144 + 4 * 8388608);          // 16 MB
  char* tail = ws + 262144 + 4 * 8388608 + 16777216;
  float* Pm   = (float*)(tail);                                    // 128 KB
  float* Pl   = (float*)(tail + 131072);                           // 128 KB
  int*   CIDX = (int*)  (tail + 262144);                           // 64 KB
  int*   Lc   = (int*)  (tail + 262144 + 65536);                   // 32 B

  wsplit_kernel<<<256, 256, 0, stream>>>(W, Whi, Wlo);
  scan_kernel<<<8, 256, 0, stream>>>(ymask, CIDX, Lc);
  proj_kernel<<<512, 256, 0, stream>>>(x, y, bias, Whi, Wlo, XP, YP);
  gather_rows_kernel<<<2048, 256, 0, stream>>>(YP, CIDX, Lc, YPc);
  gatherT_kernel<<<1024, 256, 0, stream>>>(y, CIDX, Lc, YTc);
  flash_kernel<<<512, 256, 0, stream>>>(XP, YPc, YTc, Lc, PO, Pm, Pl);
  merge_kernel<<<2048, 256, 0, stream>>>(PO, Pm, Pl, out);
}